// Round 2
// baseline (481.853 us; speedup 1.0000x reference)
//
#include <hip/hip_runtime.h>
#include <stdint.h>

#define BATCH    2000000
#define NHID     14
#define NT       4                     // 16-row n-tiles per wave -> 64 rows/wave
#define ROWS_PER_BLOCK 512             // 8 waves * 64 rows
#define NTILES   ((BATCH + ROWS_PER_BLOCK - 1) / ROWS_PER_BLOCK)   // 3907
#define NSLOT    236                   // 8 (L0) + 14*16 (hidden) + 4 (out) weight fragments
#define LDS_BYTES (NSLOT * 64 * 8)     // 120832 B -> 1 block/CU, 8 waves

typedef float    v4f __attribute__((ext_vector_type(4)));
typedef _Float16 v4h __attribute__((ext_vector_type(4)));

// All tensors are FP32 (per the reference). MFMA internals run f16.
//
// Weights as A operand (m = out-feature = lane&15, k = in-feature = quad*4+j).
// Activations as B operand (k = feature = quad*4+j, n = batch row = lane&15).
// C/D: row(=out-feature) = quad*4+reg, col(=batch) = lane&15  ==> C of layer l
// IS the B fragment of layer l+1 (reg j <-> reg r): activations never leave
// registers; zero barriers / LDS traffic in the batch loop. Bias folded into
// feature column 16 (L0) / 50 (hidden & out) with a propagating constant-1
// (W[50][50] = 1).
extern "C" __global__ __launch_bounds__(512, 2)
void mlp16(const float* __restrict__ x,
           const float* __restrict__ W0, const float* __restrict__ b0,
           const float* __restrict__ Wh, const float* __restrict__ bh,
           const float* __restrict__ Wo, const float* __restrict__ bo,
           float* __restrict__ out)
{
    extern __shared__ char smem_raw[];
    v4h* frag = (v4h*)smem_raw;        // fragment-major: [slot][lane] 8B each

    const int tid  = threadIdx.x;
    const int lane = tid & 63;
    const int wv   = tid >> 6;
    const int l15  = lane & 15;
    const int quad = lane >> 4;

    // ---------------- one-time weight staging into LDS ----------------
    for (int s = wv; s < NSLOT; s += 8) {
        float vj[4];
        if (s < 8) {                       // layer 0: W0[50][16], bias col k=16
            int kt = s >> 2, mt = s & 3, m = mt*16 + l15;
            #pragma unroll
            for (int j = 0; j < 4; ++j) {
                int k = kt*16 + quad*4 + j;
                float v = 0.f;
                if (m < 50 && k < 16)      v = W0[m*16 + k];
                else if (k == 16) { if (m < 50) v = b0[m]; else if (m == 50) v = 1.f; }
                vj[j] = v;
            }
        } else if (s < 232) {              // hidden: Wh[l][50][50], bias col 50, identity row 50
            int h = s - 8, l = h >> 4, kt = (h >> 2) & 3, mt = h & 3, m = mt*16 + l15;
            const float* W = Wh + l*2500;
            #pragma unroll
            for (int j = 0; j < 4; ++j) {
                int k = kt*16 + quad*4 + j;
                float v = 0.f;
                if (m < 50 && k < 50)      v = W[m*50 + k];
                else if (k == 50) { if (m < 50) v = bh[l*50 + m]; else if (m == 50) v = 1.f; }
                vj[j] = v;
            }
        } else {                           // output: Wo[4][50], bias col 50
            int kt = s - 232, m = l15;
            #pragma unroll
            for (int j = 0; j < 4; ++j) {
                int k = kt*16 + quad*4 + j;
                float v = 0.f;
                if (m < 4) { if (k < 50) v = Wo[m*50 + k]; else if (k == 50) v = bo[m]; }
                vj[j] = v;
            }
        }
        v4h p;
        #pragma unroll
        for (int j = 0; j < 4; ++j) p[j] = (_Float16)vj[j];
        frag[s*64 + lane] = p;
    }
    __syncthreads();                       // only barrier in the kernel

    // L0 / output A-fragments are tiny: keep resident in registers
    v4h A0[2][4], Ao[4];
    #pragma unroll
    for (int kt = 0; kt < 2; ++kt)
        #pragma unroll
        for (int mt = 0; mt < 4; ++mt) A0[kt][mt] = frag[(kt*4 + mt)*64 + lane];
    #pragma unroll
    for (int kt = 0; kt < 4; ++kt) Ao[kt] = frag[(232 + kt)*64 + lane];

    const _Float16 one = (_Float16)1.0f;

    for (int tile = blockIdx.x; tile < NTILES; tile += gridDim.x) {
        const int rowbase = tile*ROWS_PER_BLOCK + wv*64;
        v4h B[NT][4];                      // activations [n-tile][kt], registers only

        // ---- layer 0: K=32 (16 real + constant-1 slot) ----
        #pragma unroll
        for (int nt = 0; nt < NT; ++nt) {
            int r  = rowbase + nt*16 + l15;
            int rc = r < BATCH ? r : BATCH - 1;              // clamp tail loads
            v4f xv = *(const v4f*)(x + rc*16 + quad*4);      // 16B/lane, dense 1KB/wave
            v4h bx;
            #pragma unroll
            for (int j = 0; j < 4; ++j) bx[j] = (_Float16)xv[j];
            v4h b1 = { (_Float16)0, (_Float16)0, (_Float16)0, (_Float16)0 };
            if (quad == 0) b1[0] = one;                      // k==16 bias-one slot
            v4f acc[4];
            #pragma unroll
            for (int mt = 0; mt < 4; ++mt) {
                acc[mt] = (v4f){0.f,0.f,0.f,0.f};
                acc[mt] = __builtin_amdgcn_mfma_f32_16x16x16f16(A0[0][mt], bx, acc[mt], 0, 0, 0);
                acc[mt] = __builtin_amdgcn_mfma_f32_16x16x16f16(A0[1][mt], b1, acc[mt], 0, 0, 0);
            }
            #pragma unroll
            for (int kt = 0; kt < 4; ++kt) {
                v4h nb;
                #pragma unroll
                for (int j = 0; j < 4; ++j) { float v = acc[kt][j]; nb[j] = (_Float16)(v > 0.f ? v : 0.f); }
                B[nt][kt] = nb;
            }
        }

        // ---- 14 hidden layers, activations never leave registers ----
        for (int l = 0; l < NHID; ++l) {
            v4h A[4][4];
            const v4h* ab = frag + (8 + l*16)*64 + lane;
            #pragma unroll
            for (int kt = 0; kt < 4; ++kt)
                #pragma unroll
                for (int mt = 0; mt < 4; ++mt) A[kt][mt] = ab[(kt*4 + mt)*64]; // ds_read_b64, conflict-free
            #pragma unroll
            for (int nt = 0; nt < NT; ++nt) {
                v4f acc[4];
                #pragma unroll
                for (int mt = 0; mt < 4; ++mt) acc[mt] = (v4f){0.f,0.f,0.f,0.f};
                #pragma unroll
                for (int kt = 0; kt < 4; ++kt)
                    #pragma unroll
                    for (int mt = 0; mt < 4; ++mt)
                        acc[mt] = __builtin_amdgcn_mfma_f32_16x16x16f16(A[kt][mt], B[nt][kt], acc[mt], 0, 0, 0);
                #pragma unroll
                for (int kt = 0; kt < 4; ++kt) {           // relu + f16 cvt: C tile kt IS next B frag kt
                    v4h nb;
                    #pragma unroll
                    for (int j = 0; j < 4; ++j) { float v = acc[kt][j]; nb[j] = (_Float16)(v > 0.f ? v : 0.f); }
                    B[nt][kt] = nb;
                }
            }
        }

        // ---- output layer: channels 0..3 land in quad==0 lanes (reg j = channel j) ----
        #pragma unroll
        for (int nt = 0; nt < NT; ++nt) {
            v4f acc = (v4f){0.f,0.f,0.f,0.f};
            #pragma unroll
            for (int kt = 0; kt < 4; ++kt)
                acc = __builtin_amdgcn_mfma_f32_16x16x16f16(Ao[kt], B[nt][kt], acc, 0, 0, 0);
            int r = rowbase + nt*16 + l15;
            if (quad == 0 && r < BATCH) {
                *(v4f*)(out + r*4) = acc;                  // 16B store per row, fp32 out
            }
        }
    }
}

extern "C" void kernel_launch(void* const* d_in, const int* in_sizes, int n_in,
                              void* d_out, int out_size, void* d_ws, size_t ws_size,
                              hipStream_t stream)
{
    (void)in_sizes; (void)n_in; (void)d_ws; (void)ws_size; (void)out_size;
    hipFuncSetAttribute(reinterpret_cast<const void*>(mlp16),
                        hipFuncAttributeMaxDynamicSharedMemorySize, LDS_BYTES);
    mlp16<<<256, 512, LDS_BYTES, stream>>>(
        (const float*)d_in[0], (const float*)d_in[1], (const float*)d_in[2],
        (const float*)d_in[3], (const float*)d_in[4], (const float*)d_in[5],
        (const float*)d_in[6], (float*)d_out);
}

// Round 4
// 338.068 us; speedup vs baseline: 1.4253x; 1.4253x over previous
//
#include <hip/hip_runtime.h>
#include <stdint.h>

#define BATCH 2000000
#define NHID  14
#define NT    8                         // 16-row n-tiles per wave -> 128 rows/wave
#define ROWS_PER_BLOCK 1024             // 8 waves * 128
#define NTILES ((BATCH + ROWS_PER_BLOCK - 1) / ROWS_PER_BLOCK)   // 1954
#define NSLOT 118                       // 4 (L0) + 14*8 (hidden) + 2 (out) x32 A-fragments
#define LDS_BYTES (NSLOT * 64 * 16)     // 120832 B -> 1 block/CU, 8 waves

typedef float    v4f  __attribute__((ext_vector_type(4)));
typedef _Float16 v8h  __attribute__((ext_vector_type(8)));
typedef __fp16   v2p  __attribute__((ext_vector_type(2)));  // matches cvt_pkrtz return
typedef uint32_t v4u  __attribute__((ext_vector_type(4)));

// x32 MFMA layouts: A[m=lane&15][k=quad*8+j], B[k=quad*8+j][n=lane&15],
// C/D[row=quad*4+reg][col=lane&15].
// k-permutation: store A's k-columns permuted so the next-layer B fragment is
// exactly the concatenation of two packed C tiles (no cross-lane ops).
// Slot kappa = 32*t' + 8*q + j holds actual feature kown(kappa):
//   s = 8*t' + j ; kown = 16*(s>>2) + 4*q + (s&3)
// which equals the feature held by C tile (2t'+(j>>2)), reg (j&3), lane quad q.
__device__ __forceinline__ int kown(int kappa) {
    int s = ((kappa >> 5) << 3) | (kappa & 7);
    int q = (kappa >> 3) & 3;
    return ((s >> 2) << 4) | (q * 4 + (s & 3));
}

__device__ __forceinline__ uint32_t pk(float a, float b) {      // v_cvt_pkrtz_f16_f32
    union { v2p v; uint32_t u; } c;
    c.v = __builtin_amdgcn_cvt_pkrtz(a, b);
    return c.u;
}
__device__ __forceinline__ uint32_t relu_pk(float a, float b) { // pkrtz + v_pk_max_f16
    v2p z = { (__fp16)0.0f, (__fp16)0.0f };
    union { v2p v; uint32_t u; } c;
    c.v = __builtin_amdgcn_cvt_pkrtz(a, b);
    c.v = __builtin_elementwise_max(c.v, z);
    return c.u;
}

// C tiles (4 x v4f) -> two x32 B fragments (relu + f16 pack), per the
// k-permutation above. 16 VALU ops total.
__device__ __forceinline__ void pack2(const v4f* acc, v8h* Bv) {
    union { v4u u; v8h h; } c0, c1;
    c0.u.x = relu_pk(acc[0][0], acc[0][1]);
    c0.u.y = relu_pk(acc[0][2], acc[0][3]);
    c0.u.z = relu_pk(acc[1][0], acc[1][1]);
    c0.u.w = relu_pk(acc[1][2], acc[1][3]);
    c1.u.x = relu_pk(acc[2][0], acc[2][1]);
    c1.u.y = relu_pk(acc[2][2], acc[2][3]);
    c1.u.z = relu_pk(acc[3][0], acc[3][1]);
    c1.u.w = relu_pk(acc[3][2], acc[3][3]);
    Bv[0] = c0.h;
    Bv[1] = c1.h;
}

extern "C" __global__ __launch_bounds__(512, 2)
void mlp16(const float* __restrict__ x,
           const float* __restrict__ W0, const float* __restrict__ b0,
           const float* __restrict__ Wh, const float* __restrict__ bh,
           const float* __restrict__ Wo, const float* __restrict__ bo,
           float* __restrict__ out)
{
    extern __shared__ char smem_raw[];
    v8h* frag = (v8h*)smem_raw;         // [slot][lane], 16 B per lane

    const int tid  = threadIdx.x;
    const int lane = tid & 63;
    const int wv   = tid >> 6;
    const int l15  = lane & 15;
    const int quad = lane >> 4;

    // ------------- one-time weight staging (bias folded at k==50/16) -------------
    for (int s = wv; s < NSLOT; s += 8) {
        float v[8];
        if (s < 4) {                    // layer 0: natural k, K=32 (16 real + bias@16)
            int m = s * 16 + l15;
            #pragma unroll
            for (int j = 0; j < 8; ++j) {
                int kap = quad * 8 + j;
                float val = 0.f;
                if (kap < 16)      { if (m < 50) val = W0[m * 16 + kap]; }
                else if (kap == 16){ if (m < 50) val = b0[m]; else if (m == 50) val = 1.f; }
                v[j] = val;
            }
        } else if (s < 116) {           // hidden: permuted k, bias col 50, identity row 50
            int h = s - 4, l = h >> 3, t = (h >> 2) & 1, mt = h & 3;
            int m = mt * 16 + l15;
            const float* W = Wh + l * 2500;
            #pragma unroll
            for (int j = 0; j < 8; ++j) {
                int ko = kown(t * 32 + quad * 8 + j);
                float val = 0.f;
                if (ko < 50)       { if (m < 50) val = W[m * 50 + ko]; }
                else if (ko == 50) { if (m < 50) val = bh[l * 50 + m]; else if (m == 50) val = 1.f; }
                v[j] = val;
            }
        } else {                        // output: permuted k, bias col 50, m<4
            int t = s - 116, m = l15;
            #pragma unroll
            for (int j = 0; j < 8; ++j) {
                int ko = kown(t * 32 + quad * 8 + j);
                float val = 0.f;
                if (m < 4) { if (ko < 50) val = Wo[m * 50 + ko]; else if (ko == 50) val = bo[m]; }
                v[j] = val;
            }
        }
        v8h fv;
        #pragma unroll
        for (int j = 0; j < 8; ++j) fv[j] = (_Float16)v[j];   // RNE
        frag[s * 64 + lane] = fv;
    }
    __syncthreads();                    // only barrier in the kernel

    // L0 / output A-fragments: register-resident
    v8h A0[4], Ao[2];
    #pragma unroll
    for (int mt = 0; mt < 4; ++mt) A0[mt] = frag[mt * 64 + lane];
    #pragma unroll
    for (int t = 0; t < 2; ++t)    Ao[t] = frag[(116 + t) * 64 + lane];

    const v4f z4 = (v4f){0.f, 0.f, 0.f, 0.f};   // persistent zero C operand

    for (int tile = blockIdx.x; tile < NTILES; tile += gridDim.x) {
        const int rowbase = tile * ROWS_PER_BLOCK + wv * (16 * NT);
        v8h Bv[NT][2];                  // activations, registers only

        // ---- layer 0 (K=32: 16 features + bias-one at kappa=16) ----
        #pragma unroll
        for (int nt = 0; nt < NT; ++nt) {
            int r  = rowbase + nt * 16 + l15;
            int rc = r < BATCH ? r : BATCH - 1;
            union { v4u u; v8h h; } bx;
            bx.u = (v4u){0u, 0u, 0u, 0u};
            if (quad < 2) {             // lanes 0-31: 2x16B loads, 1KB dense per 16 rows
                const float* xp = x + (size_t)rc * 16 + quad * 8;
                v4f xa = *(const v4f*)xp;
                v4f xb = *(const v4f*)(xp + 4);
                bx.u.x = pk(xa[0], xa[1]);
                bx.u.y = pk(xa[2], xa[3]);
                bx.u.z = pk(xb[0], xb[1]);
                bx.u.w = pk(xb[2], xb[3]);
            } else if (quad == 2) {
                bx.u.x = 0x3C00u;       // f16 1.0 at kappa=16 (bias slot)
            }
            v4f acc[4];
            #pragma unroll
            for (int mt = 0; mt < 4; ++mt)
                acc[mt] = __builtin_amdgcn_mfma_f32_16x16x32_f16(A0[mt], bx.h, z4, 0, 0, 0);
            pack2(acc, Bv[nt]);         // relu + pack: C tiles -> x32 B frags
        }

        // ---- 14 hidden layers: 8 x32 MFMA + 16 VALU per n-tile, no LDS for acts ----
        for (int l = 0; l < NHID; ++l) {
            v8h A[2][4];
            const v8h* ab = frag + (4 + l * 8) * 64 + lane;
            #pragma unroll
            for (int t = 0; t < 2; ++t)
                #pragma unroll
                for (int mt = 0; mt < 4; ++mt) A[t][mt] = ab[(t * 4 + mt) * 64]; // ds_read_b128
            #pragma unroll
            for (int nt = 0; nt < NT; ++nt) {
                v4f acc[4];
                #pragma unroll
                for (int mt = 0; mt < 4; ++mt)
                    acc[mt] = __builtin_amdgcn_mfma_f32_16x16x32_f16(A[0][mt], Bv[nt][0], z4, 0, 0, 0);
                #pragma unroll
                for (int mt = 0; mt < 4; ++mt)
                    acc[mt] = __builtin_amdgcn_mfma_f32_16x16x32_f16(A[1][mt], Bv[nt][1], acc[mt], 0, 0, 0);
                pack2(acc, Bv[nt]);
            }
        }

        // ---- output layer: 2 MFMA per n-tile; channels 0-3 = quad-0 regs 0-3 ----
        #pragma unroll
        for (int nt = 0; nt < NT; ++nt) {
            v4f acc = __builtin_amdgcn_mfma_f32_16x16x32_f16(Ao[0], Bv[nt][0], z4, 0, 0, 0);
            acc     = __builtin_amdgcn_mfma_f32_16x16x32_f16(Ao[1], Bv[nt][1], acc, 0, 0, 0);
            int r = rowbase + nt * 16 + l15;
            if (quad == 0 && r < BATCH)
                *(v4f*)(out + (size_t)r * 4) = acc;   // 16B store per row
        }
    }
}

extern "C" void kernel_launch(void* const* d_in, const int* in_sizes, int n_in,
                              void* d_out, int out_size, void* d_ws, size_t ws_size,
                              hipStream_t stream)
{
    (void)in_sizes; (void)n_in; (void)d_ws; (void)ws_size; (void)out_size;
    (void)hipFuncSetAttribute(reinterpret_cast<const void*>(mlp16),
                              hipFuncAttributeMaxDynamicSharedMemorySize, LDS_BYTES);
    mlp16<<<256, 512, LDS_BYTES, stream>>>(
        (const float*)d_in[0], (const float*)d_in[1], (const float*)d_in[2],
        (const float*)d_in[3], (const float*)d_in[4], (const float*)d_in[5],
        (const float*)d_in[6], (float*)d_out);
}